// Round 7
// baseline (516.392 us; speedup 1.0000x reference)
//
#include <hip/hip_runtime.h>

// DYConv2d on MI355X — rank-1-factorized dynamic conv via 9 shifted GEMMs.
//   y[b,o,p] = a_oup[b,o] * Sum_k a_k[b,k] * Sum_c (W[o,c,k]*a_inp[b,c]) * x[b,c,p+off_k]
// R7: a_inp folded into per-b weights W' (bf16 hi/lo — error model unchanged);
//     x read ONCE (fused transpose+pool K1, atomic channel sums); W' b-chunked.
// R6: conv 246us @ MfmaUtil 44.5% (2-barrier ceiling), total 485us, absmax 2^-8;
//     non-conv 239us dominated by two 411MB x passes -> this round kills one.
//
// ws layout (bytes):
//   s       @ 0        (32*256 f32)  channel SUMS (fc divides by 3136)
//   a_inp   @ 32768    (32*256 f32)
//   aoup_s  @ 65536    (32*256 f32)  = sigmoid(..)*max_k a_k
//   rho     @ 98304    (32*8 f32)    = sorted ratios a_k[t]/a_k[t+1] <= 1
//   tpk     @ 99328    (32*32 int)   = per-b {kernel-tap, padded-offset}
//   xtp     @ 103424   [32][3456][256] bf16 (padded-58 transpose, UNscaled)
//   wt_hi'  @ 56726528 [CH_W][9][256][256] bf16 = base_w * a_inp[b]  (hi)
//   wt_lo'  @ +CH_W*1179648                                          (lo)

typedef __attribute__((ext_vector_type(8))) short s16x8;
typedef __attribute__((ext_vector_type(4))) float fx4;

#define PP_FIRST 59       // first valid padded flat index = (h=0+1)*58 + (w=0+1)
#define XTP_ROWS 3456     // conv reads rows [0,3445]; rows outside data zeroed

__device__ __forceinline__ unsigned short bf16_rne(float f){
  unsigned u = __builtin_bit_cast(unsigned, f);
  u += 0x7fffu + ((u >> 16) & 1u);
  return (unsigned short)(u >> 16);
}
__device__ __forceinline__ float bf16_to_f(unsigned short h){
  unsigned u = ((unsigned)h) << 16;
  return __builtin_bit_cast(float, u);
}

// ---------- K0: zero pad rows of xtp + zero s ----------
__global__ void zpad_kernel(unsigned short* __restrict__ xtp, float* __restrict__ s){
  const int slot = blockIdx.x, r = blockIdx.y;     // grid (32, 210)
  const int t = threadIdx.x;
  if(r == 0) s[(slot << 8) + t] = 0.f;             // 32*256 = 8192 = whole s
  const int row = (r < 59) ? r : (3305 + (r - 59));
  xtp[((size_t)slot * XTP_ROWS + row) * 256 + t] = 0;
}

// ---------- K1: fused transpose+pad+bf16 + channel-sum (single x pass) ----------
__global__ void xpool_kernel(const float* __restrict__ x,
                             unsigned short* __restrict__ xtp,
                             float* __restrict__ s){
  const int c0 = blockIdx.x * 64, h = blockIdx.y;  // grid (4, 56, 32)
  const int b = blockIdx.z;
  __shared__ float tile[64 * 59];                  // [c_local][w], stride 59
  const int t = threadIdx.x;
  const float* xb = x + ((size_t)b * 256 + c0) * 3136 + h * 56;
  for(int i = t; i < 1792; i += 256){              // 64 c * 28 float2
    int c = i / 28, w2 = (i % 28) * 2;
    float2 v = *(const float2*)(xb + (size_t)c * 3136 + w2);
    tile[c * 59 + w2]     = v.x;
    tile[c * 59 + w2 + 1] = v.y;
  }
  __syncthreads();
  // per-channel partial sum over this h row (4 threads per c)
  {
    const int c = t >> 2, q = t & 3;
    float sm = 0.f;
    for(int w = q; w < 56; w += 4) sm += tile[c * 59 + w];
    sm += __shfl_down(sm, 2, 4);
    sm += __shfl_down(sm, 1, 4);
    if(q == 0) atomicAdd(&s[(b << 8) + c0 + c], sm);
  }
  // bf16 transposed padded write (UNscaled)
  const size_t base = ((size_t)b * XTP_ROWS + (size_t)(h + 1) * 58) * 256 + c0;
  for(int i = t; i < 58 * 32; i += 256){           // 58 padded w-slots * 32 c-pairs
    int wp = i >> 5, cp = (i & 31) * 2;
    float v0 = 0.f, v1 = 0.f;
    if(wp >= 1 && wp <= 56){
      v0 = tile[cp * 59 + (wp - 1)];
      v1 = tile[(cp + 1) * 59 + (wp - 1)];
    }
    unsigned short h0 = bf16_rne(v0), h1 = bf16_rne(v1);
    *(unsigned*)(xtp + base + (size_t)wp * 256 + cp) = (unsigned)h0 | ((unsigned)h1 << 16);
  }
}

// ---------- K2: attention FC chain + per-b tap sort (one block) ----------
__global__ void fc_kernel(const float* __restrict__ s,
                          const float* __restrict__ shw, const float* __restrict__ shb,
                          const float* __restrict__ inw, const float* __restrict__ inb,
                          const float* __restrict__ ouw, const float* __restrict__ oub,
                          const float* __restrict__ kw,  const float* __restrict__ kb,
                          float* __restrict__ a_inp, float* __restrict__ aoup_s,
                          float* __restrict__ rho, int* __restrict__ tpk){
  __shared__ float hh[32*16];
  __shared__ float ak[32*9];
  __shared__ float akmax[32];
  const int t = threadIdx.x;
  // h = relu((s/3136) @ shw^T + shb)   (s holds channel sums)
  for(int i = t; i < 512; i += 256){
    int b = i >> 4, r = i & 15;
    float dot = 0.f;
    const float* sp = s + b*256; const float* wp = shw + r*256;
    for(int c = 0; c < 256; ++c) dot += sp[c] * wp[c];
    hh[i] = fmaxf(shb[r] + dot * (1.0f / 3136.0f), 0.f);
  }
  __syncthreads();
  // a_k
  for(int i = t; i < 288; i += 256){
    int b = i / 9, k = i % 9;
    float acc = kb[k];
    for(int r = 0; r < 16; ++r) acc += hh[b*16+r] * kw[k*16+r];
    ak[i] = 1.f / (1.f + expf(-acc));
  }
  __syncthreads();
  // sort taps ascending by a_k -> Horner rescale ratios <= 1
  if(t < 32){
    float v[9]; int id[9];
    for(int j = 0; j < 9; ++j){ v[j] = ak[t*9 + j]; id[j] = j; }
    for(int a = 1; a < 9; ++a){
      float vv = v[a]; int ii = id[a]; int p = a - 1;
      while(p >= 0 && v[p] > vv){ v[p+1] = v[p]; id[p+1] = id[p]; --p; }
      v[p+1] = vv; id[p+1] = ii;
    }
    for(int j = 0; j < 9; ++j){
      tpk[t*32 + 2*j]     = id[j];                              // kernel tap index
      tpk[t*32 + 2*j + 1] = (id[j]/3 - 1)*58 + (id[j]%3 - 1);   // padded shift
    }
    for(int j = 0; j < 8; ++j) rho[t*8 + j] = v[j] / v[j+1];    // <= 1
    akmax[t] = v[8];
  }
  __syncthreads();
  // a_inp (consumed by wsplit')
  for(int i = t; i < 8192; i += 256){
    int b = i >> 8, c = i & 255;
    float acc = inb[c];
    for(int r = 0; r < 16; ++r) acc += hh[b*16+r] * inw[c*16+r];
    a_inp[i] = 1.f / (1.f + expf(-acc));
  }
  // a_oup * max a_k
  for(int i = t; i < 8192; i += 256){
    int b = i >> 8, o = i & 255;
    float acc = oub[o];
    for(int r = 0; r < 16; ++r) acc += hh[b*16+r] * ouw[o*16+r];
    aoup_s[i] = (1.f / (1.f + expf(-acc))) * akmax[b];
  }
}

// ---------- K3: per-b scaled weights W' = base_w * a_inp[b], hi/lo bf16 ----------
__global__ void wsplit_kernel(const float* __restrict__ bw, const float* __restrict__ a_inp,
                              unsigned short* __restrict__ wt_hi,
                              unsigned short* __restrict__ wt_lo, int b0){
  const int o = blockIdx.x, slot = blockIdx.y;     // grid (256, z)
  const int c = threadIdx.x;
  const int b = b0 + slot;
  const float ai = a_inp[(b << 8) + c];
  const float* p = bw + ((size_t)o * 256 + c) * 9;
  #pragma unroll
  for(int k = 0; k < 9; ++k){
    float v = p[k] * ai;
    unsigned short h = bf16_rne(v);
    unsigned short l = bf16_rne(v - bf16_to_f(h));
    size_t idx = (((size_t)slot * 9 + k) * 256 + o) * 256 + c;
    wt_hi[idx] = h; wt_lo[idx] = l;
  }
}

// ---------- K6: conv — 9 sorted shifted GEMMs, tile 128o x 256pp ----------
// 256 thr (4 waves 2x2: 64o x 128pp each, acc 4x8), BK=64 (4 cc-steps of c).
// LDS 64KB: X@0 (256 rows x 64c), Whi@32K, Wlo@48K (128 rows x 64c each);
// rows XOR-swizzled ((row&7) on 16B granules), global_load_lds linear dest
// + pre-swizzled global source (rule #21). 2 blocks/CU.
#define GLDS(gp, lo_) __builtin_amdgcn_global_load_lds( \
    (const __attribute__((address_space(1))) void*)(gp), \
    (__attribute__((address_space(3))) void*)(lds + (lo_)), 16, 0, 0)

__launch_bounds__(256, 2)
__global__ void conv_kernel(const unsigned short* __restrict__ wt_hi,
                            const unsigned short* __restrict__ wt_lo,
                            const unsigned short* __restrict__ xtp,
                            const float* __restrict__ aoup_s,
                            const float* __restrict__ rho,
                            const int* __restrict__ tpk,
                            float* __restrict__ out, int b0){
  __shared__ unsigned char lds[65536];
  const int tile = blockIdx.x;            // 0..12
  const int o0   = blockIdx.y << 7;       // 0,128
  const int slot = blockIdx.z;            // chunk-local (W'), b global (xtp)
  const int b    = b0 + slot;
  const int pp0  = PP_FIRST + tile * 256;
  const int t    = threadIdx.x;
  const int lane = t & 63;
  const int wave = t >> 6;
  const int wm = wave >> 1, wn = wave & 1;

  fx4 acc[4][8];
  #pragma unroll
  for(int i = 0; i < 4; ++i)
    #pragma unroll
    for(int j = 0; j < 8; ++j)
      acc[i][j] = fx4{0.f, 0.f, 0.f, 0.f};

  // staging geometry: g = rnd*256+t -> row = g>>3 (64-c row = 128B = 8 granules)
  const int srow = t >> 3;                               // + rnd*32
  const int sg8  = (((t & 7) ^ ((t >> 3) & 7)) << 3);    // pre-swizzled src granule
  const int ldsu = wave << 10;                           // + rnd*4096 + region base

  // compute-side frag addresses (bytes), row-stride 128
  const int rA  = lane & 15;
  const int kg  = lane >> 4;
  const int r7  = rA & 7;
  const int gk0 = ((kg ^ r7) << 4);            // k-step 0
  const int gk1 = (((4 + kg) ^ r7) << 4);      // k-step 1
  const int aRow = ((wm << 6) + rA) * 128;     // W rows (64 per wave)
  const int bRow = ((wn << 7) + rA) * 128;     // X rows (128 per wave)

  const size_t xrow0 = (size_t)b * XTP_ROWS * 256;       // global b
  const size_t wrow0 = (size_t)slot * 9 * 65536;         // chunk-local slot

  for(int tap = 0; tap < 9; ++tap){
    if(tap > 0){
      const float rr = rho[(b << 3) + tap - 1];   // <= 1 (sorted)
      #pragma unroll
      for(int i = 0; i < 4; ++i)
        #pragma unroll
        for(int j = 0; j < 8; ++j)
          #pragma unroll
          for(int r = 0; r < 4; ++r) acc[i][j][r] *= rr;
    }
    const int pt  = tpk[(b << 5) + (tap << 1)];      // kernel tap (sorted order)
    const int off = tpk[(b << 5) + (tap << 1) + 1];  // padded-space shift
    const unsigned short* xp  = xtp + xrow0 + (size_t)(pp0 + off + srow) * 256 + sg8;
    const unsigned short* wh0 = wt_hi + wrow0 + ((size_t)(pt * 256 + o0 + srow)) * 256 + sg8;
    const unsigned short* wl0 = wt_lo + wrow0 + ((size_t)(pt * 256 + o0 + srow)) * 256 + sg8;

    for(int cc = 0; cc < 4; ++cc){
      const int co = cc << 6;
      #pragma unroll
      for(int rnd = 0; rnd < 8; ++rnd)            // X: 256 rows
        GLDS(xp + co + rnd * 8192, 0 + rnd * 4096 + ldsu);
      #pragma unroll
      for(int rnd = 0; rnd < 4; ++rnd){           // W hi/lo: 128 rows each
        GLDS(wh0 + co + rnd * 8192, 32768 + rnd * 4096 + ldsu);
        GLDS(wl0 + co + rnd * 8192, 49152 + rnd * 4096 + ldsu);
      }
      __syncthreads();   // vmcnt drained before barrier -> staged data visible
      #pragma unroll
      for(int ks = 0; ks < 2; ++ks){
        const int gk = ks ? gk1 : gk0;
        s16x8 ah[4], al[4], bh[8];
        #pragma unroll
        for(int i = 0; i < 4; ++i){
          const int ro = aRow + i * 2048 + gk;
          ah[i] = *(const s16x8*)(lds + 32768 + ro);
          al[i] = *(const s16x8*)(lds + 49152 + ro);
        }
        #pragma unroll
        for(int j = 0; j < 8; ++j)
          bh[j] = *(const s16x8*)(lds + bRow + j * 2048 + gk);
        #pragma unroll
        for(int i = 0; i < 4; ++i)
          #pragma unroll
          for(int j = 0; j < 8; ++j){
            acc[i][j] = __builtin_amdgcn_mfma_f32_16x16x32_bf16(ah[i], bh[j], acc[i][j], 0, 0, 0);
            acc[i][j] = __builtin_amdgcn_mfma_f32_16x16x32_bf16(al[i], bh[j], acc[i][j], 0, 0, 0);
          }
      }
      __syncthreads();   // compute done before next stage overwrites
    }
  }

  // epilogue: * a_oup[b,o]*max_ak; map padded pp -> (h,w); drop pad rows/cols
  float sc[4][4];
  #pragma unroll
  for(int i = 0; i < 4; ++i){
    const int ob = o0 + (wm << 6) + i * 16 + (kg << 2);
    #pragma unroll
    for(int r = 0; r < 4; ++r) sc[i][r] = aoup_s[(b << 8) + ob + r];
  }
  #pragma unroll
  for(int j = 0; j < 8; ++j){
    const int pp = pp0 + (wn << 7) + j * 16 + rA;
    const int hp = pp / 58, wp = pp % 58;
    if(hp >= 1 && hp <= 56 && wp >= 1 && wp <= 56){
      const int p = (hp - 1) * 56 + (wp - 1);
      #pragma unroll
      for(int i = 0; i < 4; ++i){
        const int ob = o0 + (wm << 6) + i * 16 + (kg << 2);
        float* op = out + ((size_t)((b << 8) + ob)) * 3136 + p;
        #pragma unroll
        for(int r = 0; r < 4; ++r) op[(size_t)r * 3136] = acc[i][j][r] * sc[i][r];
      }
    }
  }
}

extern "C" void kernel_launch(void* const* d_in, const int* in_sizes, int n_in,
                              void* d_out, int out_size, void* d_ws, size_t ws_size,
                              hipStream_t stream){
  const float* x   = (const float*)d_in[0];
  const float* bw  = (const float*)d_in[1];
  const float* shw = (const float*)d_in[2];
  const float* shb = (const float*)d_in[3];
  const float* inw = (const float*)d_in[4];
  const float* inb = (const float*)d_in[5];
  const float* ouw = (const float*)d_in[6];
  const float* oub = (const float*)d_in[7];
  const float* kw  = (const float*)d_in[8];
  const float* kb  = (const float*)d_in[9];
  float* out = (float*)d_out;

  char* ws = (char*)d_ws;
  float* s      = (float*)(ws);
  float* a_inp  = (float*)(ws + 32768);
  float* aoup_s = (float*)(ws + 65536);
  float* rho    = (float*)(ws + 98304);
  int*   tpk    = (int*)(ws + 99328);
  unsigned short* xtp   = (unsigned short*)(ws + 103424);
  unsigned short* wt_hi = (unsigned short*)(ws + 56726528);  // 103424 + 32*3456*256*2

  // W'-chunk policy (ws_size constant per process -> fixed launch sequence).
  // Proven ws >= 115.7MB (R4/R6) -> CH_W >= 25; if ws >= 132.3MB, one chunk of 32.
  const size_t WBYTES = 2359296;                   // per-sample hi+lo
  size_t chw = (ws_size > 56726528) ? (ws_size - 56726528) / WBYTES : 1;
  if(chw > 32) chw = 32; if(chw < 1) chw = 1;
  const int CH_W = (int)chw;
  unsigned short* wt_lo = wt_hi + (size_t)CH_W * 9 * 65536;

  hipLaunchKernelGGL(zpad_kernel,  dim3(32, 210), dim3(256), 0, stream, xtp, s);
  hipLaunchKernelGGL(xpool_kernel, dim3(4, 56, 32), dim3(256), 0, stream, x, xtp, s);
  hipLaunchKernelGGL(fc_kernel,    dim3(1), dim3(256), 0, stream,
                     s, shw, shb, inw, inb, ouw, oub, kw, kb, a_inp, aoup_s, rho, tpk);
  for(int b0 = 0; b0 < 32; b0 += CH_W){
    const int z = (32 - b0 < CH_W) ? (32 - b0) : CH_W;
    hipLaunchKernelGGL(wsplit_kernel, dim3(256, z), dim3(256), 0, stream,
                       bw, a_inp, wt_hi, wt_lo, b0);
    hipLaunchKernelGGL(conv_kernel,   dim3(13, 2, z), dim3(256), 0, stream,
                       wt_hi, wt_lo, xtp, aoup_s, rho, tpk, out, b0);
  }
}

// Round 9
// 508.870 us; speedup vs baseline: 1.0148x; 1.0148x over previous
//
#include <hip/hip_runtime.h>

// DYConv2d on MI355X — rank-1-factorized dynamic conv via 9 shifted GEMMs.
//   y[b,o,p] = a_oup[b,o] * Sum_k a_k[b,k] * Sum_c W[o,c,k] * (a_inp[b,c]*x[b,c,p+off_k])
// R9 = R8 resubmitted unchanged (infra failure; never ran; desk audit clean).
// R8: single x pass (xpool: unscaled bf16 hi + compact residual lo + channel
//     sums) -> fc -> xscale ((hi+lo)*a_inp, ONE rounding = R6 numerics) ->
//     R6 conv verbatim (SHARED W hi/lo — R7's per-b W' broke L2 residency:
//     FETCH 501->790MB, conv 246->277us; reverted).
// R6 best: total 485us (conv 246 @ MfmaUtil 44.5%, non-conv 239).
//
// ws layout (bytes):
//   s      @ 0         (32*256 f32)  channel SUMS (fc divides by 3136)
//   a_inp  @ 32768     (32*256 f32)
//   aoup_s @ 65536     (32*256 f32)  = sigmoid(..)*max_k a_k
//   rho    @ 98304     (32*8 f32)    sorted ratios a_k[t]/a_k[t+1] <= 1
//   tpk    @ 99328     (32*32 int)   per-b {kernel-tap, padded-offset}
//   xtp    @ 103424    [32][3456][256] bf16 padded-58 transpose (scaled in place)
//   xlo    @ 56726528  [32][3136][256] bf16 residual x - bf16(x), data rows only
//   wt_hi  @ 108106752 [9][256][256] bf16 (shared, c-contig)
//   wt_lo  @ 109286400 [9][256][256] bf16
//   total 110,466,048 <= proven ws 115.7MB

typedef __attribute__((ext_vector_type(8))) short s16x8;
typedef __attribute__((ext_vector_type(4))) float fx4;

#define PP_FIRST 59
#define XTP_ROWS 3456

__device__ __forceinline__ unsigned short bf16_rne(float f){
  unsigned u = __builtin_bit_cast(unsigned, f);
  u += 0x7fffu + ((u >> 16) & 1u);
  return (unsigned short)(u >> 16);
}
__device__ __forceinline__ float bf16_to_f(unsigned short h){
  unsigned u = ((unsigned)h) << 16;
  return __builtin_bit_cast(float, u);
}

// ---------- K0: zero pad rows of xtp + zero s ----------
__global__ void zpad_kernel(unsigned short* __restrict__ xtp, float* __restrict__ s){
  const int slot = blockIdx.x, r = blockIdx.y;     // grid (32, 210)
  const int t = threadIdx.x;
  if(r == 0) s[(slot << 8) + t] = 0.f;
  const int row = (r < 59) ? r : (3305 + (r - 59));
  xtp[((size_t)slot * XTP_ROWS + row) * 256 + t] = 0;
}

// ---------- K1: fused transpose+pad+bf16-split + channel-sum (single x pass) ----------
__global__ void xpool_kernel(const float* __restrict__ x,
                             unsigned short* __restrict__ xtp,
                             unsigned short* __restrict__ xlo,
                             float* __restrict__ s){
  const int c0 = blockIdx.x * 64, h = blockIdx.y;  // grid (4, 56, 32)
  const int b = blockIdx.z;
  __shared__ float tile[64 * 59];                  // [c_local][w], stride 59
  const int t = threadIdx.x;
  const float* xb = x + ((size_t)b * 256 + c0) * 3136 + h * 56;
  for(int i = t; i < 1792; i += 256){              // 64 c * 28 float2
    int c = i / 28, w2 = (i % 28) * 2;
    float2 v = *(const float2*)(xb + (size_t)c * 3136 + w2);
    tile[c * 59 + w2]     = v.x;
    tile[c * 59 + w2 + 1] = v.y;
  }
  __syncthreads();
  // per-channel partial sum over this h row (4 threads per c)
  {
    const int c = t >> 2, q = t & 3;
    float sm = 0.f;
    for(int w = q; w < 56; w += 4) sm += tile[c * 59 + w];
    sm += __shfl_down(sm, 2, 4);
    sm += __shfl_down(sm, 1, 4);
    if(q == 0) atomicAdd(&s[(b << 8) + c0 + c], sm);
  }
  // bf16 hi (padded layout) + residual lo (compact data layout)
  const size_t base = ((size_t)b * XTP_ROWS + (size_t)(h + 1) * 58) * 256 + c0;
  for(int i = t; i < 58 * 32; i += 256){           // 58 padded w-slots * 32 c-pairs
    int wp = i >> 5, cp = (i & 31) * 2;
    float v0 = 0.f, v1 = 0.f;
    if(wp >= 1 && wp <= 56){
      v0 = tile[cp * 59 + (wp - 1)];
      v1 = tile[(cp + 1) * 59 + (wp - 1)];
    }
    unsigned short h0 = bf16_rne(v0), h1 = bf16_rne(v1);
    *(unsigned*)(xtp + base + (size_t)wp * 256 + cp) = (unsigned)h0 | ((unsigned)h1 << 16);
    if(wp >= 1 && wp <= 56){
      unsigned short l0 = bf16_rne(v0 - bf16_to_f(h0));
      unsigned short l1 = bf16_rne(v1 - bf16_to_f(h1));
      size_t li = (((size_t)b * 3136) + h * 56 + (wp - 1)) * 256 + c0 + cp;
      *(unsigned*)(xlo + li) = (unsigned)l0 | ((unsigned)l1 << 16);
    }
  }
}

// ---------- K2: attention FC chain + per-b tap sort (one block) ----------
__global__ void fc_kernel(const float* __restrict__ s,
                          const float* __restrict__ shw, const float* __restrict__ shb,
                          const float* __restrict__ inw, const float* __restrict__ inb,
                          const float* __restrict__ ouw, const float* __restrict__ oub,
                          const float* __restrict__ kw,  const float* __restrict__ kb,
                          float* __restrict__ a_inp, float* __restrict__ aoup_s,
                          float* __restrict__ rho, int* __restrict__ tpk){
  __shared__ float hh[32*16];
  __shared__ float ak[32*9];
  __shared__ float akmax[32];
  const int t = threadIdx.x;
  for(int i = t; i < 512; i += 256){               // h = relu((s/3136)@shw^T+shb)
    int b = i >> 4, r = i & 15;
    float dot = 0.f;
    const float* sp = s + b*256; const float* wp = shw + r*256;
    for(int c = 0; c < 256; ++c) dot += sp[c] * wp[c];
    hh[i] = fmaxf(shb[r] + dot * (1.0f / 3136.0f), 0.f);
  }
  __syncthreads();
  for(int i = t; i < 288; i += 256){               // a_k
    int b = i / 9, k = i % 9;
    float acc = kb[k];
    for(int r = 0; r < 16; ++r) acc += hh[b*16+r] * kw[k*16+r];
    ak[i] = 1.f / (1.f + expf(-acc));
  }
  __syncthreads();
  if(t < 32){  // sort taps ascending by a_k -> Horner ratios <= 1
    float v[9]; int id[9];
    for(int j = 0; j < 9; ++j){ v[j] = ak[t*9 + j]; id[j] = j; }
    for(int a = 1; a < 9; ++a){
      float vv = v[a]; int ii = id[a]; int p = a - 1;
      while(p >= 0 && v[p] > vv){ v[p+1] = v[p]; id[p+1] = id[p]; --p; }
      v[p+1] = vv; id[p+1] = ii;
    }
    for(int j = 0; j < 9; ++j){
      tpk[t*32 + 2*j]     = id[j];
      tpk[t*32 + 2*j + 1] = (id[j]/3 - 1)*58 + (id[j]%3 - 1);
    }
    for(int j = 0; j < 8; ++j) rho[t*8 + j] = v[j] / v[j+1];
    akmax[t] = v[8];
  }
  __syncthreads();
  for(int i = t; i < 8192; i += 256){              // a_inp
    int b = i >> 8, c = i & 255;
    float acc = inb[c];
    for(int r = 0; r < 16; ++r) acc += hh[b*16+r] * inw[c*16+r];
    a_inp[i] = 1.f / (1.f + expf(-acc));
  }
  for(int i = t; i < 8192; i += 256){              // a_oup * max a_k
    int b = i >> 8, o = i & 255;
    float acc = oub[o];
    for(int r = 0; r < 16; ++r) acc += hh[b*16+r] * ouw[o*16+r];
    aoup_s[i] = (1.f / (1.f + expf(-acc))) * akmax[b];
  }
}

// ---------- K3: xscale — xtp = bf16((hi+lo) * a_inp)  (one rounding) ----------
__global__ void xscale_kernel(unsigned short* __restrict__ xtp,
                              const unsigned short* __restrict__ xlo,
                              const float* __restrict__ a_inp){
  const int h = blockIdx.x, b = blockIdx.y;        // grid (56, 32)
  const int t = threadIdx.x;
  __shared__ float as[256];
  as[t] = a_inp[(b << 8) + t];
  __syncthreads();
  // 56 w-rows * 128 c-pairs = 7168 u32 per block
  for(int p = t; p < 7168; p += 256){
    const int w = p >> 7, cp2 = p & 127;           // c = cp2*2
    const int g = (h + 1) * 58 + (w + 1);
    unsigned* hp = (unsigned*)(xtp + ((size_t)b * XTP_ROWS + g) * 256 + cp2 * 2);
    const unsigned lo = *(const unsigned*)(xlo + (((size_t)b * 3136) + h * 56 + w) * 256 + cp2 * 2);
    const unsigned hi = *hp;
    const float v0 = (bf16_to_f((unsigned short)hi) + bf16_to_f((unsigned short)lo)) * as[cp2*2];
    const float v1 = (bf16_to_f((unsigned short)(hi >> 16)) + bf16_to_f((unsigned short)(lo >> 16))) * as[cp2*2+1];
    *hp = (unsigned)bf16_rne(v0) | ((unsigned)bf16_rne(v1) << 16);
  }
}

// ---------- K4: base_w split -> Wt[k][o][c] hi/lo bf16 (shared) ----------
__global__ void wsplit_kernel(const float* __restrict__ bw,
                              unsigned short* __restrict__ wt_hi,
                              unsigned short* __restrict__ wt_lo){
  const int i = blockIdx.x * 256 + threadIdx.x;    // (o,c)
  const float* p = bw + (size_t)i * 9;
  const int o = i >> 8, c = i & 255;
  #pragma unroll
  for(int k = 0; k < 9; ++k){
    float v = p[k];
    unsigned short h = bf16_rne(v);
    unsigned short l = bf16_rne(v - bf16_to_f(h));
    size_t idx = ((size_t)k << 16) + ((size_t)o << 8) + c;
    wt_hi[idx] = h; wt_lo[idx] = l;
  }
}

// ---------- K6: conv — R6 verbatim (9 sorted GEMMs, 128o x 256pp, shared W) ----------
#define GLDS(gp, lo_) __builtin_amdgcn_global_load_lds( \
    (const __attribute__((address_space(1))) void*)(gp), \
    (__attribute__((address_space(3))) void*)(lds + (lo_)), 16, 0, 0)

__launch_bounds__(256, 2)
__global__ void conv_kernel(const unsigned short* __restrict__ wt_hi,
                            const unsigned short* __restrict__ wt_lo,
                            const unsigned short* __restrict__ xtp,
                            const float* __restrict__ aoup_s,
                            const float* __restrict__ rho,
                            const int* __restrict__ tpk,
                            float* __restrict__ out){
  __shared__ unsigned char lds[65536];
  const int tile = blockIdx.x;            // 0..12
  const int o0   = blockIdx.y << 7;       // 0,128
  const int b    = blockIdx.z;
  const int pp0  = PP_FIRST + tile * 256;
  const int t    = threadIdx.x;
  const int lane = t & 63;
  const int wave = t >> 6;
  const int wm = wave >> 1, wn = wave & 1;

  fx4 acc[4][8];
  #pragma unroll
  for(int i = 0; i < 4; ++i)
    #pragma unroll
    for(int j = 0; j < 8; ++j)
      acc[i][j] = fx4{0.f, 0.f, 0.f, 0.f};

  const int srow = t >> 3;
  const int sg8  = (((t & 7) ^ ((t >> 3) & 7)) << 3);
  const int ldsu = wave << 10;

  const int rA  = lane & 15;
  const int kg  = lane >> 4;
  const int r7  = rA & 7;
  const int gk0 = ((kg ^ r7) << 4);
  const int gk1 = (((4 + kg) ^ r7) << 4);
  const int aRow = ((wm << 6) + rA) * 128;
  const int bRow = ((wn << 7) + rA) * 128;

  const size_t xrow0 = (size_t)b * XTP_ROWS * 256;

  for(int tap = 0; tap < 9; ++tap){
    if(tap > 0){
      const float rr = rho[(b << 3) + tap - 1];
      #pragma unroll
      for(int i = 0; i < 4; ++i)
        #pragma unroll
        for(int j = 0; j < 8; ++j)
          #pragma unroll
          for(int r = 0; r < 4; ++r) acc[i][j][r] *= rr;
    }
    const int pt  = tpk[(b << 5) + (tap << 1)];
    const int off = tpk[(b << 5) + (tap << 1) + 1];
    const unsigned short* xp  = xtp + xrow0 + (size_t)(pp0 + off + srow) * 256 + sg8;
    const unsigned short* wh0 = wt_hi + ((size_t)(pt * 256 + o0 + srow)) * 256 + sg8;
    const unsigned short* wl0 = wt_lo + ((size_t)(pt * 256 + o0 + srow)) * 256 + sg8;

    for(int cc = 0; cc < 4; ++cc){
      const int co = cc << 6;
      #pragma unroll
      for(int rnd = 0; rnd < 8; ++rnd)
        GLDS(xp + co + rnd * 8192, 0 + rnd * 4096 + ldsu);
      #pragma unroll
      for(int rnd = 0; rnd < 4; ++rnd){
        GLDS(wh0 + co + rnd * 8192, 32768 + rnd * 4096 + ldsu);
        GLDS(wl0 + co + rnd * 8192, 49152 + rnd * 4096 + ldsu);
      }
      __syncthreads();
      #pragma unroll
      for(int ks = 0; ks < 2; ++ks){
        const int gk = ks ? gk1 : gk0;
        s16x8 ah[4], al[4], bh[8];
        #pragma unroll
        for(int i = 0; i < 4; ++i){
          const int ro = aRow + i * 2048 + gk;
          ah[i] = *(const s16x8*)(lds + 32768 + ro);
          al[i] = *(const s16x8*)(lds + 49152 + ro);
        }
        #pragma unroll
        for(int j = 0; j < 8; ++j)
          bh[j] = *(const s16x8*)(lds + bRow + j * 2048 + gk);
        #pragma unroll
        for(int i = 0; i < 4; ++i)
          #pragma unroll
          for(int j = 0; j < 8; ++j){
            acc[i][j] = __builtin_amdgcn_mfma_f32_16x16x32_bf16(ah[i], bh[j], acc[i][j], 0, 0, 0);
            acc[i][j] = __builtin_amdgcn_mfma_f32_16x16x32_bf16(al[i], bh[j], acc[i][j], 0, 0, 0);
          }
      }
      __syncthreads();
    }
  }

  float sc[4][4];
  #pragma unroll
  for(int i = 0; i < 4; ++i){
    const int ob = o0 + (wm << 6) + i * 16 + (kg << 2);
    #pragma unroll
    for(int r = 0; r < 4; ++r) sc[i][r] = aoup_s[(b << 8) + ob + r];
  }
  #pragma unroll
  for(int j = 0; j < 8; ++j){
    const int pp = pp0 + (wn << 7) + j * 16 + rA;
    const int hp = pp / 58, wp = pp % 58;
    if(hp >= 1 && hp <= 56 && wp >= 1 && wp <= 56){
      const int p = (hp - 1) * 56 + (wp - 1);
      #pragma unroll
      for(int i = 0; i < 4; ++i){
        const int ob = o0 + (wm << 6) + i * 16 + (kg << 2);
        float* op = out + ((size_t)((b << 8) + ob)) * 3136 + p;
        #pragma unroll
        for(int r = 0; r < 4; ++r) op[(size_t)r * 3136] = acc[i][j][r] * sc[i][r];
      }
    }
  }
}

extern "C" void kernel_launch(void* const* d_in, const int* in_sizes, int n_in,
                              void* d_out, int out_size, void* d_ws, size_t ws_size,
                              hipStream_t stream){
  const float* x   = (const float*)d_in[0];
  const float* bw  = (const float*)d_in[1];
  const float* shw = (const float*)d_in[2];
  const float* shb = (const float*)d_in[3];
  const float* inw = (const float*)d_in[4];
  const float* inb = (const float*)d_in[5];
  const float* ouw = (const float*)d_in[6];
  const float* oub = (const float*)d_in[7];
  const float* kw  = (const float*)d_in[8];
  const float* kb  = (const float*)d_in[9];
  float* out = (float*)d_out;

  char* ws = (char*)d_ws;
  float* s      = (float*)(ws);
  float* a_inp  = (float*)(ws + 32768);
  float* aoup_s = (float*)(ws + 65536);
  float* rho    = (float*)(ws + 98304);
  int*   tpk    = (int*)(ws + 99328);
  unsigned short* xtp   = (unsigned short*)(ws + 103424);
  unsigned short* xlo   = (unsigned short*)(ws + 56726528);
  unsigned short* wt_hi = (unsigned short*)(ws + 108106752);
  unsigned short* wt_lo = (unsigned short*)(ws + 109286400);
  // total 110,466,048 B <= proven ws (R4 ran the >=115,704,832 path)

  hipLaunchKernelGGL(zpad_kernel,   dim3(32, 210),   dim3(256), 0, stream, xtp, s);
  hipLaunchKernelGGL(xpool_kernel,  dim3(4, 56, 32), dim3(256), 0, stream, x, xtp, xlo, s);
  hipLaunchKernelGGL(wsplit_kernel, dim3(256),       dim3(256), 0, stream, bw, wt_hi, wt_lo);
  hipLaunchKernelGGL(fc_kernel,     dim3(1),         dim3(256), 0, stream,
                     s, shw, shb, inw, inb, ouw, oub, kw, kb, a_inp, aoup_s, rho, tpk);
  hipLaunchKernelGGL(xscale_kernel, dim3(56, 32),    dim3(256), 0, stream, xtp, xlo, a_inp);
  hipLaunchKernelGGL(conv_kernel,   dim3(13, 2, 32), dim3(256), 0, stream,
                     wt_hi, wt_lo, xtp, aoup_s, rho, tpk, out);
}